// Round 20
// baseline (33.267 us; speedup 1.0000x reference)
//
#include <hip/hip_runtime.h>

// out(p) = (49 - g·G)/8,  g = x/max(||x||_C,1e-8),
// G = 7x7 zero-padded box-sum of g (separable 7-tap H then V).
// Wave-autonomous 64x16 tiles (2 out rows/lane), NO block barrier.
// 22 h-rows per 16 out rows (1.375x halo). LDS [hr][grp] conflict-free.
// Own h-rows folded from registers (18 LDS reads).
// NEW (r20): 2-wave (128-thread) blocks — the kernel is wave-autonomous, so
// block size is free. LDS/block halves to 16,896 B -> 9 blocks/CU resident
// (18 waves/CU vs 16 with 4-wave blocks; LDS was the binding cap).

typedef unsigned int u32;
typedef float f32x2 __attribute__((ext_vector_type(2)));
typedef float f32x4 __attribute__((ext_vector_type(4)));

#define EPS2 1e-16f   // 1/max(sqrt(n2),1e-8) == rsq(max(n2,1e-16))

constexpr int HRN = 22;   // h rows per wave tile (16 out rows + 6 halo)

__device__ __forceinline__ u32 packbf2(float a, float b) {
    // round-half-up bf16 pack (a=lo, b=hi) via v_perm_b32
    const u32 ua = __float_as_uint(a) + 0x8000u;
    const u32 ub = __float_as_uint(b) + 0x8000u;
    return __builtin_amdgcn_perm(ub, ua, 0x07060302u);
}
__device__ __forceinline__ float uplo(u32 u) { return __uint_as_float(u << 16); }
__device__ __forceinline__ float uphi(u32 u) { return __uint_as_float(u & 0xffff0000u); }
__device__ __forceinline__ f32x2 up2(u32 u) {
    f32x2 r; r.x = uplo(u); r.y = uphi(u); return r;
}
__device__ __forceinline__ f32x4 vmul(f32x4 v, float s) {
    f32x4 r; r[0]=v[0]*s; r[1]=v[1]*s; r[2]=v[2]*s; r[3]=v[3]*s; return r;
}

__global__ __launch_bounds__(128, 3) void mcnd_kernel(const float* __restrict__ x,
                                                      float* __restrict__ out,
                                                      int B, int H, int W) {
    // wave-private h: [wave][ch][hr][grp], uint4 = 8 bf16 cols. 16,896 B.
    __shared__ uint4 hsh[2][3][HRN][8];

    const int HW = H * W;
    const int tilesX = W >> 6;                     // 8  (block tile 64x32)
    const int tilesPerImg = tilesX * (H >> 5);     // 128

    // bijective XCD swizzle (grid 4096 % 8 == 0)
    const int cpx  = gridDim.x >> 3;
    const int wgid = (blockIdx.x & 7) * cpx + (blockIdx.x >> 3);
    const int b    = wgid / tilesPerImg;
    const int t    = wgid % tilesPerImg;
    const int ty   = t / tilesX;                   // 0..15 (32-row block strip)
    const int tx   = t - ty * tilesX;
    const int x0   = tx << 6;

    const int wv   = threadIdx.x >> 6;             // wave id (0,1): 16-row strip
    const int lane = threadIdx.x & 63;
    const int r2   = lane >> 3;                    // 0..7 -> out rows 2r2, 2r2+1
    const int grp  = lane & 7;                     // 8-col group
    const int yw   = (ty << 5) + (wv << 4);        // wave's first out row

    const float* __restrict__ xb = x + (size_t)b * 3 * HW;

    // column geometry (cols gxl..gxl+15 cover out cols 8grp with +/-3 halo)
    const int   gxl   = x0 + (grp << 3) - 4;       // 16B-aligned
    const float lmask = (gxl >= 0) ? 1.f : 0.f;
    const float rmask = (gxl + 16 <= W) ? 1.f : 0.f;
    const int   gofL  = (gxl >= 0) ? gxl : 0;              // clamped, in-bounds
    const int   gofR  = (gxl + 16 <= W) ? (gxl + 12) : (W - 4);

    u32 gA0[4], gA1[4], gA2[4];                    // center g, out row 2r2
    u32 gB0[4], gB1[4], gB2[4];                    // center g, out row 2r2+1
    uint4 hA[3], hB[3];                            // own h rows (packed bf16)

    // h-row hr corresponds to global row yw + hr - 3
    auto process = [&](int hr, u32* cp0, u32* cp1, u32* cp2, uint4* hcap) {
        const int   gy  = yw + hr - 3;
        const float rmk = (gy >= 0 && gy < H) ? 1.f : 0.f;
        const int   gyc = gy < 0 ? 0 : (gy >= H ? H - 1 : gy);
        const float* rp0 = xb + (size_t)gyc * W;
        const float* rp1 = rp0 + HW;
        const float* rp2 = rp1 + HW;
        // unconditional loads from clamped (always valid) addresses
        f32x4 a0 = *(const f32x4*)(rp0 + gofL);
        f32x4 a1 = *(const f32x4*)(rp0 + gxl + 4);
        f32x4 a2 = *(const f32x4*)(rp0 + gxl + 8);
        f32x4 a3 = *(const f32x4*)(rp0 + gofR);
        f32x4 b0 = *(const f32x4*)(rp1 + gofL);
        f32x4 b1 = *(const f32x4*)(rp1 + gxl + 4);
        f32x4 b2 = *(const f32x4*)(rp1 + gxl + 8);
        f32x4 b3 = *(const f32x4*)(rp1 + gofR);
        f32x4 c0 = *(const f32x4*)(rp2 + gofL);
        f32x4 c1 = *(const f32x4*)(rp2 + gxl + 4);
        f32x4 c2 = *(const f32x4*)(rp2 + gxl + 8);
        f32x4 c3 = *(const f32x4*)(rp2 + gofR);
        // zero out-of-image column chunks (finite values -> 0*v == 0)
        a0 = vmul(a0, lmask); b0 = vmul(b0, lmask); c0 = vmul(c0, lmask);
        a3 = vmul(a3, rmask); b3 = vmul(b3, rmask); c3 = vmul(c3, rmask);
        // per-column inverse norm (row mask folded in)
        f32x4 i0, i1, i2, i3;
        {
            const f32x4 n0 = a0*a0 + b0*b0 + c0*c0;
            const f32x4 n1 = a1*a1 + b1*b1 + c1*c1;
            const f32x4 n2 = a2*a2 + b2*b2 + c2*c2;
            const f32x4 n3 = a3*a3 + b3*b3 + c3*c3;
#pragma unroll
            for (int e = 0; e < 4; ++e) {
                i0[e] = __builtin_amdgcn_rsqf(fmaxf(n0[e], EPS2)) * rmk;
                i1[e] = __builtin_amdgcn_rsqf(fmaxf(n1[e], EPS2)) * rmk;
                i2[e] = __builtin_amdgcn_rsqf(fmaxf(n2[e], EPS2)) * rmk;
                i3[e] = __builtin_amdgcn_rsqf(fmaxf(n3[e], EPS2)) * rmk;
            }
        }
        auto chan = [&](const f32x4& A0, const f32x4& A1, const f32x4& A2,
                        const f32x4& A3, int ch, u32* gcp, uint4* hc) {
            float cc[16];
#pragma unroll
            for (int e = 0; e < 4; ++e) {
                cc[e]      = A0[e] * i0[e];
                cc[4 + e]  = A1[e] * i1[e];
                cc[8 + e]  = A2[e] * i2[e];
                cc[12 + e] = A3[e] * i3[e];
            }
            // h for out col 8grp+m: staged cols m+1..m+7
            float hp[8];
            hp[0] = cc[1]+cc[2]+cc[3]+cc[4]+cc[5]+cc[6]+cc[7];
#pragma unroll
            for (int m = 1; m < 8; ++m) hp[m] = hp[m-1] - cc[m] + cc[m+7];
            uint4 hwv;
            hwv.x = packbf2(hp[0], hp[1]); hwv.y = packbf2(hp[2], hp[3]);
            hwv.z = packbf2(hp[4], hp[5]); hwv.w = packbf2(hp[6], hp[7]);
            hsh[wv][ch][hr][grp] = hwv;
            if (hc) *hc = hwv;                     // own h row kept in regs
            if (gcp) {                             // center g = local cols 4..11
                gcp[0] = packbf2(cc[4],  cc[5]);
                gcp[1] = packbf2(cc[6],  cc[7]);
                gcp[2] = packbf2(cc[8],  cc[9]);
                gcp[3] = packbf2(cc[10], cc[11]);
            }
        };
        chan(a0, a1, a2, a3, 0, cp0, hcap ? &hcap[0] : nullptr);
        chan(b0, b1, b2, b3, 1, cp1, hcap ? &hcap[1] : nullptr);
        chan(c0, c1, c2, c3, 2, cp2, hcap ? &hcap[2] : nullptr);
    };

    // own output rows: hr = 2r2+3 (out row 2r2), hr = 2r2+4 (out row 2r2+1)
    process(2*r2 + 3, gA0, gA1, gA2, hA);
    process(2*r2 + 4, gB0, gB1, gB2, hB);
    // halo rows {0,1,2,19,20,21} on lanes 0..47
    if (lane < 48) {
        const int rr = lane >> 3;                  // 0..5
        process(rr < 3 ? rr : rr + 16, nullptr, nullptr, nullptr, nullptr);
    }
    // wave-local fence instead of __syncthreads (wave reads only hsh[wv])
    asm volatile("s_waitcnt lgkmcnt(0)" ::: "memory");
    __builtin_amdgcn_sched_barrier(0);

    // ---- vertical 7-tap, sliding over the 2 out rows; own rows from regs ----
    f32x2 D0[4], D1[4];
#pragma unroll
    for (int e = 0; e < 4; ++e) { D0[e] = f32x2{0.f,0.f}; D1[e] = f32x2{0.f,0.f}; }
    auto vch = [&](int ch, const u32* ga, const u32* gb) {
        const uint4 u0 = hsh[wv][ch][2*r2][grp];       // d = 0
        f32x2 s0 = up2(u0.x), s1 = up2(u0.y), s2 = up2(u0.z), s3 = up2(u0.w);
#pragma unroll
        for (int d = 1; d < 3; ++d) {                  // d = 1, 2 from LDS
            const uint4 u = hsh[wv][ch][2*r2 + d][grp];
            s0 += up2(u.x); s1 += up2(u.y); s2 += up2(u.z); s3 += up2(u.w);
        }
        // d = 3, 4: own rows from registers
        s0 += up2(hA[ch].x) + up2(hB[ch].x);
        s1 += up2(hA[ch].y) + up2(hB[ch].y);
        s2 += up2(hA[ch].z) + up2(hB[ch].z);
        s3 += up2(hA[ch].w) + up2(hB[ch].w);
#pragma unroll
        for (int d = 5; d < 7; ++d) {                  // d = 5, 6 from LDS
            const uint4 u = hsh[wv][ch][2*r2 + d][grp];
            s0 += up2(u.x); s1 += up2(u.y); s2 += up2(u.z); s3 += up2(u.w);
        }
        const uint4 u7 = hsh[wv][ch][2*r2 + 7][grp];   // d = 7
        // row 2r2: window d 0..6 = s ; row 2r2+1: s - u0 + u7
        D0[0] += up2(ga[0]) * s0;
        D0[1] += up2(ga[1]) * s1;
        D0[2] += up2(ga[2]) * s2;
        D0[3] += up2(ga[3]) * s3;
        D1[0] += up2(gb[0]) * (s0 - up2(u0.x) + up2(u7.x));
        D1[1] += up2(gb[1]) * (s1 - up2(u0.y) + up2(u7.y));
        D1[2] += up2(gb[2]) * (s2 - up2(u0.z) + up2(u7.z));
        D1[3] += up2(gb[3]) * (s3 - up2(u0.w) + up2(u7.w));
    };
    vch(0, gA0, gB0); vch(1, gA1, gB1); vch(2, gA2, gB2);

    f32x4 o00, o01, o10, o11;
#pragma unroll
    for (int e = 0; e < 4; ++e) {
        const f32x2 v0 = (f32x2{49.f, 49.f} - D0[e]) * 0.125f;
        const f32x2 v1 = (f32x2{49.f, 49.f} - D1[e]) * 0.125f;
        if (e < 2) { o00[2*e] = v0.x; o00[2*e+1] = v0.y;
                     o10[2*e] = v1.x; o10[2*e+1] = v1.y; }
        else       { o01[2*(e-2)] = v0.x; o01[2*(e-2)+1] = v0.y;
                     o11[2*(e-2)] = v1.x; o11[2*(e-2)+1] = v1.y; }
    }
    float* op = out + (size_t)b * HW + (size_t)(yw + 2*r2) * W + (x0 + (grp << 3));
    *(f32x4*)(op)         = o00;                   // 8 lanes = 256B span
    *(f32x4*)(op + 4)     = o01;
    *(f32x4*)(op + W)     = o10;
    *(f32x4*)(op + W + 4) = o11;
}

extern "C" void kernel_launch(void* const* d_in, const int* in_sizes, int n_in,
                              void* d_out, int out_size, void* d_ws, size_t ws_size,
                              hipStream_t stream) {
    (void)n_in; (void)d_ws; (void)ws_size; (void)out_size;
    const float* x = (const float*)d_in[0];
    float* out = (float*)d_out;

    const int H = 512, W = 512, C = 3;
    const int B = in_sizes[0] / (C * H * W);       // 32

    const int tilesPerImg = (W >> 6) * (H >> 5);   // 128  (block tile 64x32)
    mcnd_kernel<<<B * tilesPerImg, 128, 0, stream>>>(x, out, B, H, W);
}

// Round 21
// 30.967 us; speedup vs baseline: 1.0743x; 1.0743x over previous
//
#include <hip/hip_runtime.h>

// out(p) = (49 - g·G)/8,  g = x/max(||x||_C,1e-8),
// G = 7x7 zero-padded box-sum of g (separable 7-tap H then V).
// Wave-autonomous 64x16 tiles (2 out rows/lane), NO block barrier.
// 22 h-rows per 16 out rows (1.375x halo). LDS [hr][grp] conflict-free.
// launch_bounds(256,3) (VGPR cap 170 — the (256,4)=128 cap spills, proven r15).
// The two own h-rows (hr=2r2+3, 2r2+4) are kept packed in registers and
// folded into the vertical sum directly -> 18 LDS reads instead of 24.
// [FINAL: session best = this kernel, 31.09-31.23 us (r16/r19). Closed levers:
//  barriers (r9/r17), VGPR-capped occupancy (r7/r10/r15 spill), 2-wave blocks
//  (r20 -2.2), pipelining (r13 neutral), persistent waves (r12), edge
//  specialization (r18 neutral). Serial-issue model Sum~30us == measured.]

typedef unsigned int u32;
typedef float f32x2 __attribute__((ext_vector_type(2)));
typedef float f32x4 __attribute__((ext_vector_type(4)));

#define EPS2 1e-16f   // 1/max(sqrt(n2),1e-8) == rsq(max(n2,1e-16))

constexpr int HRN = 22;   // h rows per wave tile (16 out rows + 6 halo)

__device__ __forceinline__ u32 packbf2(float a, float b) {
    // round-half-up bf16 pack (a=lo, b=hi) via v_perm_b32
    const u32 ua = __float_as_uint(a) + 0x8000u;
    const u32 ub = __float_as_uint(b) + 0x8000u;
    return __builtin_amdgcn_perm(ub, ua, 0x07060302u);
}
__device__ __forceinline__ float uplo(u32 u) { return __uint_as_float(u << 16); }
__device__ __forceinline__ float uphi(u32 u) { return __uint_as_float(u & 0xffff0000u); }
__device__ __forceinline__ f32x2 up2(u32 u) {
    f32x2 r; r.x = uplo(u); r.y = uphi(u); return r;
}
__device__ __forceinline__ f32x4 vmul(f32x4 v, float s) {
    f32x4 r; r[0]=v[0]*s; r[1]=v[1]*s; r[2]=v[2]*s; r[3]=v[3]*s; return r;
}

__global__ __launch_bounds__(256, 3) void mcnd_kernel(const float* __restrict__ x,
                                                      float* __restrict__ out,
                                                      int B, int H, int W) {
    // wave-private h: [wave][ch][hr][grp], uint4 = 8 bf16 cols. 33,792 B.
    __shared__ uint4 hsh[4][3][HRN][8];

    const int HW = H * W;
    const int tilesX = W >> 6;                     // 8  (block tile 64x64)
    const int tilesPerImg = tilesX * (H >> 6);     // 64

    // bijective XCD swizzle (grid 2048 % 8 == 0)
    const int cpx  = gridDim.x >> 3;
    const int wgid = (blockIdx.x & 7) * cpx + (blockIdx.x >> 3);
    const int b    = wgid / tilesPerImg;
    const int t    = wgid % tilesPerImg;
    const int ty   = t / tilesX;
    const int tx   = t - ty * tilesX;
    const int x0   = tx << 6;

    const int wv   = threadIdx.x >> 6;             // wave id: 16-row strip
    const int lane = threadIdx.x & 63;
    const int r2   = lane >> 3;                    // 0..7 -> out rows 2r2, 2r2+1
    const int grp  = lane & 7;                     // 8-col group
    const int yw   = (ty << 6) + (wv << 4);        // wave's first out row

    const float* __restrict__ xb = x + (size_t)b * 3 * HW;

    // column geometry (cols gxl..gxl+15 cover out cols 8grp with +/-3 halo)
    const int   gxl   = x0 + (grp << 3) - 4;       // 16B-aligned
    const float lmask = (gxl >= 0) ? 1.f : 0.f;
    const float rmask = (gxl + 16 <= W) ? 1.f : 0.f;
    const int   gofL  = (gxl >= 0) ? gxl : 0;              // clamped, in-bounds
    const int   gofR  = (gxl + 16 <= W) ? (gxl + 12) : (W - 4);

    u32 gA0[4], gA1[4], gA2[4];                    // center g, out row 2r2
    u32 gB0[4], gB1[4], gB2[4];                    // center g, out row 2r2+1
    uint4 hA[3], hB[3];                            // own h rows (packed bf16)

    // h-row hr corresponds to global row yw + hr - 3
    auto process = [&](int hr, u32* cp0, u32* cp1, u32* cp2, uint4* hcap) {
        const int   gy  = yw + hr - 3;
        const float rmk = (gy >= 0 && gy < H) ? 1.f : 0.f;
        const int   gyc = gy < 0 ? 0 : (gy >= H ? H - 1 : gy);
        const float* rp0 = xb + (size_t)gyc * W;
        const float* rp1 = rp0 + HW;
        const float* rp2 = rp1 + HW;
        // unconditional loads from clamped (always valid) addresses
        f32x4 a0 = *(const f32x4*)(rp0 + gofL);
        f32x4 a1 = *(const f32x4*)(rp0 + gxl + 4);
        f32x4 a2 = *(const f32x4*)(rp0 + gxl + 8);
        f32x4 a3 = *(const f32x4*)(rp0 + gofR);
        f32x4 b0 = *(const f32x4*)(rp1 + gofL);
        f32x4 b1 = *(const f32x4*)(rp1 + gxl + 4);
        f32x4 b2 = *(const f32x4*)(rp1 + gxl + 8);
        f32x4 b3 = *(const f32x4*)(rp1 + gofR);
        f32x4 c0 = *(const f32x4*)(rp2 + gofL);
        f32x4 c1 = *(const f32x4*)(rp2 + gxl + 4);
        f32x4 c2 = *(const f32x4*)(rp2 + gxl + 8);
        f32x4 c3 = *(const f32x4*)(rp2 + gofR);
        // zero out-of-image column chunks (finite values -> 0*v == 0)
        a0 = vmul(a0, lmask); b0 = vmul(b0, lmask); c0 = vmul(c0, lmask);
        a3 = vmul(a3, rmask); b3 = vmul(b3, rmask); c3 = vmul(c3, rmask);
        // per-column inverse norm (row mask folded in)
        f32x4 i0, i1, i2, i3;
        {
            const f32x4 n0 = a0*a0 + b0*b0 + c0*c0;
            const f32x4 n1 = a1*a1 + b1*b1 + c1*c1;
            const f32x4 n2 = a2*a2 + b2*b2 + c2*c2;
            const f32x4 n3 = a3*a3 + b3*b3 + c3*c3;
#pragma unroll
            for (int e = 0; e < 4; ++e) {
                i0[e] = __builtin_amdgcn_rsqf(fmaxf(n0[e], EPS2)) * rmk;
                i1[e] = __builtin_amdgcn_rsqf(fmaxf(n1[e], EPS2)) * rmk;
                i2[e] = __builtin_amdgcn_rsqf(fmaxf(n2[e], EPS2)) * rmk;
                i3[e] = __builtin_amdgcn_rsqf(fmaxf(n3[e], EPS2)) * rmk;
            }
        }
        auto chan = [&](const f32x4& A0, const f32x4& A1, const f32x4& A2,
                        const f32x4& A3, int ch, u32* gcp, uint4* hc) {
            float cc[16];
#pragma unroll
            for (int e = 0; e < 4; ++e) {
                cc[e]      = A0[e] * i0[e];
                cc[4 + e]  = A1[e] * i1[e];
                cc[8 + e]  = A2[e] * i2[e];
                cc[12 + e] = A3[e] * i3[e];
            }
            // h for out col 8grp+m: staged cols m+1..m+7
            float hp[8];
            hp[0] = cc[1]+cc[2]+cc[3]+cc[4]+cc[5]+cc[6]+cc[7];
#pragma unroll
            for (int m = 1; m < 8; ++m) hp[m] = hp[m-1] - cc[m] + cc[m+7];
            uint4 hwv;
            hwv.x = packbf2(hp[0], hp[1]); hwv.y = packbf2(hp[2], hp[3]);
            hwv.z = packbf2(hp[4], hp[5]); hwv.w = packbf2(hp[6], hp[7]);
            hsh[wv][ch][hr][grp] = hwv;
            if (hc) *hc = hwv;                     // own h row kept in regs
            if (gcp) {                             // center g = local cols 4..11
                gcp[0] = packbf2(cc[4],  cc[5]);
                gcp[1] = packbf2(cc[6],  cc[7]);
                gcp[2] = packbf2(cc[8],  cc[9]);
                gcp[3] = packbf2(cc[10], cc[11]);
            }
        };
        chan(a0, a1, a2, a3, 0, cp0, hcap ? &hcap[0] : nullptr);
        chan(b0, b1, b2, b3, 1, cp1, hcap ? &hcap[1] : nullptr);
        chan(c0, c1, c2, c3, 2, cp2, hcap ? &hcap[2] : nullptr);
    };

    // own output rows: hr = 2r2+3 (out row 2r2), hr = 2r2+4 (out row 2r2+1)
    process(2*r2 + 3, gA0, gA1, gA2, hA);
    process(2*r2 + 4, gB0, gB1, gB2, hB);
    // halo rows {0,1,2,19,20,21} on lanes 0..47
    if (lane < 48) {
        const int rr = lane >> 3;                  // 0..5
        process(rr < 3 ? rr : rr + 16, nullptr, nullptr, nullptr, nullptr);
    }
    // wave-local fence instead of __syncthreads (wave reads only hsh[wv])
    asm volatile("s_waitcnt lgkmcnt(0)" ::: "memory");
    __builtin_amdgcn_sched_barrier(0);

    // ---- vertical 7-tap, sliding over the 2 out rows; own rows from regs ----
    f32x2 D0[4], D1[4];
#pragma unroll
    for (int e = 0; e < 4; ++e) { D0[e] = f32x2{0.f,0.f}; D1[e] = f32x2{0.f,0.f}; }
    auto vch = [&](int ch, const u32* ga, const u32* gb) {
        const uint4 u0 = hsh[wv][ch][2*r2][grp];       // d = 0
        f32x2 s0 = up2(u0.x), s1 = up2(u0.y), s2 = up2(u0.z), s3 = up2(u0.w);
#pragma unroll
        for (int d = 1; d < 3; ++d) {                  // d = 1, 2 from LDS
            const uint4 u = hsh[wv][ch][2*r2 + d][grp];
            s0 += up2(u.x); s1 += up2(u.y); s2 += up2(u.z); s3 += up2(u.w);
        }
        // d = 3, 4: own rows from registers
        s0 += up2(hA[ch].x) + up2(hB[ch].x);
        s1 += up2(hA[ch].y) + up2(hB[ch].y);
        s2 += up2(hA[ch].z) + up2(hB[ch].z);
        s3 += up2(hA[ch].w) + up2(hB[ch].w);
#pragma unroll
        for (int d = 5; d < 7; ++d) {                  // d = 5, 6 from LDS
            const uint4 u = hsh[wv][ch][2*r2 + d][grp];
            s0 += up2(u.x); s1 += up2(u.y); s2 += up2(u.z); s3 += up2(u.w);
        }
        const uint4 u7 = hsh[wv][ch][2*r2 + 7][grp];   // d = 7
        // row 2r2: window d 0..6 = s ; row 2r2+1: s - u0 + u7
        D0[0] += up2(ga[0]) * s0;
        D0[1] += up2(ga[1]) * s1;
        D0[2] += up2(ga[2]) * s2;
        D0[3] += up2(ga[3]) * s3;
        D1[0] += up2(gb[0]) * (s0 - up2(u0.x) + up2(u7.x));
        D1[1] += up2(gb[1]) * (s1 - up2(u0.y) + up2(u7.y));
        D1[2] += up2(gb[2]) * (s2 - up2(u0.z) + up2(u7.z));
        D1[3] += up2(gb[3]) * (s3 - up2(u0.w) + up2(u7.w));
    };
    vch(0, gA0, gB0); vch(1, gA1, gB1); vch(2, gA2, gB2);

    f32x4 o00, o01, o10, o11;
#pragma unroll
    for (int e = 0; e < 4; ++e) {
        const f32x2 v0 = (f32x2{49.f, 49.f} - D0[e]) * 0.125f;
        const f32x2 v1 = (f32x2{49.f, 49.f} - D1[e]) * 0.125f;
        if (e < 2) { o00[2*e] = v0.x; o00[2*e+1] = v0.y;
                     o10[2*e] = v1.x; o10[2*e+1] = v1.y; }
        else       { o01[2*(e-2)] = v0.x; o01[2*(e-2)+1] = v0.y;
                     o11[2*(e-2)] = v1.x; o11[2*(e-2)+1] = v1.y; }
    }
    float* op = out + (size_t)b * HW + (size_t)(yw + 2*r2) * W + (x0 + (grp << 3));
    *(f32x4*)(op)         = o00;                   // 8 lanes = 256B span
    *(f32x4*)(op + 4)     = o01;
    *(f32x4*)(op + W)     = o10;
    *(f32x4*)(op + W + 4) = o11;
}

extern "C" void kernel_launch(void* const* d_in, const int* in_sizes, int n_in,
                              void* d_out, int out_size, void* d_ws, size_t ws_size,
                              hipStream_t stream) {
    (void)n_in; (void)d_ws; (void)ws_size; (void)out_size;
    const float* x = (const float*)d_in[0];
    float* out = (float*)d_out;

    const int H = 512, W = 512, C = 3;
    const int B = in_sizes[0] / (C * H * W);       // 32

    const int tilesPerImg = (W >> 6) * (H >> 6);   // 64
    mcnd_kernel<<<B * tilesPerImg, 256, 0, stream>>>(x, out, B, H, W);
}